// Round 5
// baseline (1453.199 us; speedup 1.0000x reference)
//
#include <hip/hip_runtime.h>
#include <math.h>

// ---- problem constants ----
// B=32, H=W=56, C=256, WS=7, SHIFT=3, HEADS=8, HD=32, HIDDEN=1024
// N=49 tokens/window, NW=64 windows/img, WT=2048 windows, T=100352 tokens
static constexpr long T_TOK = 100352;

typedef __attribute__((ext_vector_type(8))) short short8;
typedef __attribute__((ext_vector_type(8))) unsigned short ushort8v;
typedef __attribute__((ext_vector_type(4))) float floatx4;

__device__ __forceinline__ float b2f(unsigned short u) {
    return __uint_as_float(((unsigned)u) << 16);
}
__device__ __forceinline__ unsigned short f2b(float f) {
    unsigned u = __float_as_uint(f);
    u += 0x7FFFu + ((u >> 16) & 1u);     // round-to-nearest-even
    return (unsigned short)(u >> 16);
}

// ---- dtype detector: flag = 1 if inputs are fp32 (confirmed), 0 if bf16.
__global__ void detect_kernel(const unsigned short* __restrict__ x, int* flag) {
    __shared__ int cnt;
    if (threadIdx.x == 0) cnt = 0;
    __syncthreads();
    int local = 0;
    for (int i = 0; i < 16; ++i) {
        float a = fabsf(b2f(x[threadIdx.x * 16 + i]));
        if (a >= 0.015625f && a <= 8.0f) local++;
    }
    atomicAdd(&cnt, local);
    __syncthreads();
    if (threadIdx.x == 0) *flag = (cnt < 3072) ? 1 : 0;
}

// ---- normalize a param tensor to bf16 in ws ----
__global__ void conv_kernel(const void* __restrict__ src, unsigned short* __restrict__ dst,
                            int n, const int* __restrict__ flag) {
    int i = blockIdx.x * 256 + threadIdx.x;
    if (i >= n) return;
    if (*flag) dst[i] = f2b(((const float*)src)[i]);
    else       dst[i] = ((const unsigned short*)src)[i];
}

// ---- normalize + transpose weight [K][N] -> bf16 [N][K] ----
__global__ void convT_kernel(const void* __restrict__ src, unsigned short* __restrict__ dst,
                             int K, int N, const int* __restrict__ flag) {
    int i = blockIdx.x * 256 + threadIdx.x;
    if (i >= K * N) return;
    int k = i / N, n = i - k * N;
    unsigned short v = (*flag) ? f2b(((const float*)src)[i])
                               : ((const unsigned short*)src)[i];
    dst[(long)n * K + k] = v;
}

// ---------------- LayerNorm (one wave per token, 4 ch/lane) ----------------
__global__ __launch_bounds__(256) void ln_kernel(
    const void* __restrict__ xin,
    const unsigned short* __restrict__ g,
    const unsigned short* __restrict__ bsh,
    unsigned short* __restrict__ out, int mode, const int* __restrict__ flagp)
{
    int lane = threadIdx.x & 63;
    int wv = threadIdx.x >> 6;
    long t = (long)blockIdx.x * 4 + wv;
    int c0 = lane * 4;
    bool f32 = flagp && (*flagp != 0);
    float v0, v1, v2, v3;
    if (f32) {
        float4 xv = *(const float4*)((const float*)xin + t * 256 + c0);
        v0 = xv.x; v1 = xv.y; v2 = xv.z; v3 = xv.w;
    } else {
        ushort4 xv = *(const ushort4*)((const unsigned short*)xin + t * 256 + c0);
        v0 = b2f(xv.x); v1 = b2f(xv.y); v2 = b2f(xv.z); v3 = b2f(xv.w);
    }
    float s1 = v0 + v1 + v2 + v3;
    float s2 = v0*v0 + v1*v1 + v2*v2 + v3*v3;
    #pragma unroll
    for (int off = 32; off > 0; off >>= 1) {
        s1 += __shfl_down(s1, off, 64);
        s2 += __shfl_down(s2, off, 64);
    }
    s1 = __shfl(s1, 0, 64);
    s2 = __shfl(s2, 0, 64);
    float mean = s1 * (1.0f / 256.0f);
    float var  = s2 * (1.0f / 256.0f) - mean * mean;
    float rs = rsqrtf(fmaxf(var, 0.0f) + 1e-5f);
    ushort4 gv = *(const ushort4*)(g + c0);
    ushort4 bv = *(const ushort4*)(bsh + c0);
    ushort4 ov;
    ov.x = f2b((v0 - mean) * rs * b2f(gv.x) + b2f(bv.x));
    ov.y = f2b((v1 - mean) * rs * b2f(gv.y) + b2f(bv.y));
    ov.z = f2b((v2 - mean) * rs * b2f(gv.z) + b2f(bv.z));
    ov.w = f2b((v3 - mean) * rs * b2f(gv.w) + b2f(bv.w));
    long oidx;
    if (mode == 0) {
        int b_ = (int)(t / 3136);
        int hw = (int)(t % 3136);
        int hh = hw / 56, wc = hw % 56;
        int i = hh - 3; if (i < 0) i += 56;   // roll(-3)
        int j = wc - 3; if (j < 0) j += 56;
        oidx = ((long)(b_ * 64 + (i / 7) * 8 + (j / 7)) * 49
                + (i % 7) * 7 + (j % 7)) * 256 + c0;
    } else {
        oidx = t * 256 + c0;
    }
    *(ushort4*)(out + oidx) = ov;
}

// ------------- MFMA GEMM: 128x128 tile, 4 waves, bf16 in, fp32 acc -------------
// LDS-FREE streaming GEMM. Rationale (r4 counters): activations are L3-resident
// (fc1 FETCH 28.7MB vs 51MB logical A-read) and weights are L2-resident
// (<=0.5MB), so LDS staging saves no HBM traffic -- it only costs the per-K-step
// vmcnt(0)+barrier drain that pinned MfmaUtil at 8.4%. Here both A and B
// fragments are read directly from global (16B/lane, each 64B cacheline fully
// consumed by 4 q-lanes), 2-deep register double-buffer, ZERO barriers in the
// K-loop. Waves are fully independent; latency hidden by ILP (8 loads in
// flight per half-step) + TLP (no LDS occupancy limit).
__global__ __launch_bounds__(256) void gemm_mfma(
    const unsigned short* __restrict__ A,
    const unsigned short* __restrict__ Bt,
    const unsigned short* __restrict__ bias,
    void* __restrict__ out,
    const void* __restrict__ res,
    int M, int N, int K, int mode,
    const int* __restrict__ resflag, const int* __restrict__ oflag)
{
    const int tid  = threadIdx.x;
    const int lane = tid & 63, wave = tid >> 6;
    const int q = lane >> 4, l16 = lane & 15;
    const int wm = wave >> 1, wn = wave & 1;
    const long m0 = (long)blockIdx.y * 128;
    const int  n0 = blockIdx.x * 128;

    floatx4 acc[4][4];
    #pragma unroll
    for (int i = 0; i < 4; ++i)
        #pragma unroll
        for (int j = 0; j < 4; ++j)
            acc[i][j] = (floatx4){0.f, 0.f, 0.f, 0.f};

    // per-strip fragment base pointers (16B aligned: K*2B is 512/2048B)
    const unsigned short* Ap[4];
    const unsigned short* Bp[4];
    #pragma unroll
    for (int i = 0; i < 4; ++i)
        Ap[i] = A + (m0 + wm * 64 + i * 16 + l16) * (long)K + q * 8;
    #pragma unroll
    for (int j = 0; j < 4; ++j)
        Bp[j] = Bt + (long)(n0 + wn * 64 + j * 16 + l16) * K + q * 8;

    // K is a multiple of 64 for all launches (256 or 1024).
    short8 a0[4], b0[4], a1[4], b1[4];
    #pragma unroll
    for (int i = 0; i < 4; ++i) a0[i] = *(const short8*)(Ap[i]);
    #pragma unroll
    for (int j = 0; j < 4; ++j) b0[j] = *(const short8*)(Bp[j]);

    #pragma unroll 1
    for (int k0 = 0; k0 < K; k0 += 64) {
        #pragma unroll
        for (int i = 0; i < 4; ++i) a1[i] = *(const short8*)(Ap[i] + k0 + 32);
        #pragma unroll
        for (int j = 0; j < 4; ++j) b1[j] = *(const short8*)(Bp[j] + k0 + 32);
        #pragma unroll
        for (int i = 0; i < 4; ++i)
            #pragma unroll
            for (int j = 0; j < 4; ++j)
                acc[i][j] = __builtin_amdgcn_mfma_f32_16x16x32_bf16(
                    a0[i], b0[j], acc[i][j], 0, 0, 0);
        if (k0 + 64 < K) {
            #pragma unroll
            for (int i = 0; i < 4; ++i) a0[i] = *(const short8*)(Ap[i] + k0 + 64);
            #pragma unroll
            for (int j = 0; j < 4; ++j) b0[j] = *(const short8*)(Bp[j] + k0 + 64);
        }
        #pragma unroll
        for (int i = 0; i < 4; ++i)
            #pragma unroll
            for (int j = 0; j < 4; ++j)
                acc[i][j] = __builtin_amdgcn_mfma_f32_16x16x32_bf16(
                    a1[i], b1[j], acc[i][j], 0, 0, 0);
    }

    const bool resf32 = resflag && (*resflag != 0);
    const bool outf32 = oflag && (*oflag != 0);
    unsigned short* outb = (unsigned short*)out;
    float* outf = (float*)out;
    #pragma unroll
    for (int i = 0; i < 4; ++i) {
        #pragma unroll
        for (int r = 0; r < 4; ++r) {
            long grow = m0 + wm * 64 + i * 16 + q * 4 + r;
            long natRow = 0;
            if (mode == 1) {
                int w = (int)(grow / 49), n = (int)(grow % 49);
                int b_ = w >> 6, widx = w & 63;
                int wi = widx >> 3, wj = widx & 7;
                int pi = n / 7, pj = n % 7;
                int ii = wi * 7 + pi, jj = wj * 7 + pj;
                int h = ii + 3; if (h >= 56) h -= 56;
                int wc = jj + 3; if (wc >= 56) wc -= 56;
                natRow = ((long)b_ * 3136 + h * 56 + wc);
            }
            #pragma unroll
            for (int j = 0; j < 4; ++j) {
                int gcol = n0 + wn * 64 + j * 16 + l16;
                float v = acc[i][j][r] + b2f(bias[gcol]);
                if (mode == 2) {
                    v = 0.5f * v * (1.0f + erff(v * 0.70710678118654752f));
                    outb[grow * N + gcol] = f2b(v);
                } else if (mode == 0) {
                    outb[grow * N + gcol] = f2b(v);
                } else if (mode == 3) {
                    long o = grow * N + gcol;
                    float rv = outf32 ? outf[o] : b2f(((const unsigned short*)res)[o]);
                    v += rv;
                    if (outf32) outf[o] = v; else outb[o] = f2b(v);
                } else { // mode 1
                    long o = natRow * 256 + gcol;
                    float rv = resf32 ? ((const float*)res)[o]
                                      : b2f(((const unsigned short*)res)[o]);
                    v += rv;
                    if (outf32) outf[o] = v; else outb[o] = f2b(v);
                }
            }
        }
    }
}

// ---------------- MFMA attention: one wave per (window, head) ----------------
// 49 -> padded 64. QK^T: 4x4 tiles of 16x16x32 (HD=32 = one K-step).
// Softmax in registers (row = 16 lanes x 4 regs, shfl_xor<16 stays in quad group).
// P: LDS round-trip C-layout -> [query][key] rows (stride 72 = 16B-aligned).
// V: staged transposed [d][key] (zero-padded past 49) as PV B-operand.
__global__ __launch_bounds__(256) void attn_mfma(
    const unsigned short* __restrict__ qkv,      // [WT*49, 768] bf16
    const unsigned short* __restrict__ rel_bias, // [169, 8] bf16
    unsigned short* __restrict__ out)            // [WT*49, 256] bf16
{
    __shared__ __align__(16) unsigned short bias_s[1360];
    __shared__ __align__(16) unsigned short Vt[4][32][72];
    __shared__ __align__(16) unsigned short Ps[4][64][72];
    const int tid = threadIdx.x;
    const int lane = tid & 63, wave = tid >> 6;
    const int q = lane >> 4, l16 = lane & 15;
    const int unit = blockIdx.x * 4 + wave;      // 0..16383
    const int w = unit >> 3, h = unit & 7;
    const int widx = w & 63, wi = widx >> 3, wj = widx & 7;

    for (int e = tid; e < 1352; e += 256) bias_s[e] = rel_bias[e];

    // stage V^T: Vt[d][key] = V[key][d]; zero for key >= 49 (LDS is uninit!)
    const long vbase = (long)w * 49 * 768 + 512 + h * 32;
    #pragma unroll 4
    for (int it = 0; it < 32; ++it) {
        int idx = it * 64 + lane;                // 0..2047
        int key = idx >> 5, d = idx & 31;
        unsigned short v = (key < 49) ? qkv[vbase + (long)key * 768 + d]
                                      : (unsigned short)0;
        Vt[wave][d][key] = v;
    }
    __syncthreads();

    // Q/K fragments straight from global (rows clamped to 48)
    const long qbase = (long)w * 49 * 768 + h * 32;
    short8 qf[4], kf[4];
    #pragma unroll
    for (int i = 0; i < 4; ++i) {
        int qr = l16 + 16 * i; if (qr > 48) qr = 48;
        qf[i] = *(const short8*)(qkv + qbase + (long)qr * 768 + q * 8);
    }
    #pragma unroll
    for (int j = 0; j < 4; ++j) {
        int kr = l16 + 16 * j; if (kr > 48) kr = 48;
        kf[j] = *(const short8*)(qkv + qbase + 256 + (long)kr * 768 + q * 8);
    }

    // scores: S[query][key], C-layout row=q*4+r(+16i), col=l16(+16j)
    floatx4 sc[4][4];
    #pragma unroll
    for (int i = 0; i < 4; ++i)
        #pragma unroll
        for (int j = 0; j < 4; ++j)
            sc[i][j] = __builtin_amdgcn_mfma_f32_16x16x32_bf16(
                qf[i], kf[j], (floatx4){0.f, 0.f, 0.f, 0.f}, 0, 0, 0);

    // key-side precompute (depends on j,l16 only)
    int imj[4], jmj[4], tmj[4], validj[4];
    #pragma unroll
    for (int j = 0; j < 4; ++j) {
        int key = 16 * j + l16;
        validj[j] = key < 49;
        int k2 = validj[j] ? key : 48;
        int im = k2 / 7, jm = k2 - im * 7;
        imj[j] = im; jmj[j] = jm;
        int rm = wi * 7 + im, cm = wj * 7 + jm;
        tmj[j] = (rm < 49 ? 0 : (rm < 53 ? 1 : 2)) * 3
               + (cm < 49 ? 0 : (cm < 53 ? 1 : 2));
    }

    const float scale = 0.17677669529663687f;    // HD^-0.5
    #pragma unroll
    for (int i = 0; i < 4; ++i) {
        #pragma unroll
        for (int r = 0; r < 4; ++r) {
            int query = 16 * i + 4 * q + r;
            int qn = query > 48 ? 48 : query;
            int in_ = qn / 7, jn = qn - in_ * 7;
            int rn = wi * 7 + in_, cn = wj * 7 + jn;
            int tn = (rn < 49 ? 0 : (rn < 53 ? 1 : 2)) * 3
                   + (cn < 49 ? 0 : (cn < 53 ? 1 : 2));
            float sv[4];
            float mx = -1e30f;
            #pragma unroll
            for (int j = 0; j < 4; ++j) {
                float s = sc[i][j][r] * scale;
                int ridx = (imj[j] - in_ + 6) * 13 + (jmj[j] - jn + 6);
                s += b2f(bias_s[ridx * 8 + h]);
                if (tmj[j] != tn) s -= 100.0f;
                if (!validj[j]) s = -1e30f;
                sv[j] = s;
                mx = fmaxf(mx, s);
            }
            #pragma unroll
            for (int m = 1; m < 16; m <<= 1)
                mx = fmaxf(mx, __shfl_xor(mx, m, 64));
            float sum = 0.0f;
            #pragma unroll
            for (int j = 0; j < 4; ++j) { sv[j] = __expf(sv[j] - mx); sum += sv[j]; }
            #pragma unroll
            for (int m = 1; m < 16; m <<= 1)
                sum += __shfl_xor(sum, m, 64);
            float inv = 1.0f / sum;
            #pragma unroll
            for (int j = 0; j < 4; ++j)
                Ps[wave][query][16 * j + l16] = f2b(sv[j] * inv);
        }
    }
    // wave-local LDS: compiler inserts lgkmcnt waits; no barrier needed.

    // PV: O[query][d] = P @ V. A=P from Ps rows, B=V from Vt rows.
    floatx4 oacc[4][2];
    #pragma unroll
    for (int i = 0; i < 4; ++i)
        #pragma unroll
        for (int jd = 0; jd < 2; ++jd)
            oacc[i][jd] = (floatx4){0.f, 0.f, 0.f, 0.f};
    #pragma unroll
    for (int s = 0; s < 2; ++s) {
        short8 vfr[2];
        #pragma unroll
        for (int jd = 0; jd < 2; ++jd)
            vfr[jd] = *(const short8*)&Vt[wave][l16 + 16 * jd][32 * s + q * 8];
        #pragma unroll
        for (int i = 0; i < 4; ++i) {
            short8 pfr = *(const short8*)&Ps[wave][l16 + 16 * i][32 * s + q * 8];
            #pragma unroll
            for (int jd = 0; jd < 2; ++jd)
                oacc[i][jd] = __builtin_amdgcn_mfma_f32_16x16x32_bf16(
                    pfr, vfr[jd], oacc[i][jd], 0, 0, 0);
        }
    }

    const long obase = (long)w * 49 * 256 + h * 32;
    #pragma unroll
    for (int i = 0; i < 4; ++i) {
        #pragma unroll
        for (int r = 0; r < 4; ++r) {
            int query = 16 * i + 4 * q + r;
            if (query < 49) {
                #pragma unroll
                for (int jd = 0; jd < 2; ++jd)
                    out[obase + (long)query * 256 + 16 * jd + l16] =
                        f2b(oacc[i][jd][r]);
            }
        }
    }
}

extern "C" void kernel_launch(void* const* d_in, const int* in_sizes, int n_in,
                              void* d_out, int out_size, void* d_ws, size_t ws_size,
                              hipStream_t stream) {
    (void)n_in; (void)out_size; (void)ws_size; (void)in_sizes;
    unsigned short* ws  = (unsigned short*)d_ws;
    const size_t TT = (size_t)T_TOK;

    unsigned short* r0  = ws;                        // [T,256]: xw / attn_out / x2n
    unsigned short* r1  = ws + TT * 256;             // [T,1024]: qkv then hidden
    unsigned short* pb  = ws + TT * 256 + TT * 1024; // params (weights transposed)
    const size_t O_QKVW = 0,      O_QKVB = 196608, O_RELB = 197376, O_PROJW = 198728;
    const size_t O_PROJB = 264264, O_N1G = 264520, O_N1B = 264776;
    const size_t O_N2G = 265032,  O_N2B = 265288, O_FC1W = 265544, O_FC1B = 527688;
    const size_t O_FC2W = 528712, O_FC2B = 790856, O_PEND = 791112;
    int* flag = (int*)(pb + O_PEND);

    detect_kernel<<<1, 256, 0, stream>>>((const unsigned short*)d_in[0], flag);

    struct { int idx; size_t off; int n; } cv[9] = {
        {1, O_N1G, 256}, {2, O_N1B, 256}, {4, O_QKVB, 768},
        {5, O_RELB, 1352}, {7, O_PROJB, 256},
        {8, O_N2G, 256}, {9, O_N2B, 256}, {11, O_FC1B, 1024}, {13, O_FC2B, 256},
    };
    for (int i = 0; i < 9; ++i)
        conv_kernel<<<(cv[i].n + 255) / 256, 256, 0, stream>>>(
            d_in[cv[i].idx], pb + cv[i].off, cv[i].n, flag);
    convT_kernel<<<(196608 + 255) / 256, 256, 0, stream>>>(d_in[3],  pb + O_QKVW, 256, 768,  flag);
    convT_kernel<<<(65536  + 255) / 256, 256, 0, stream>>>(d_in[6],  pb + O_PROJW, 256, 256, flag);
    convT_kernel<<<(262144 + 255) / 256, 256, 0, stream>>>(d_in[10], pb + O_FC1W, 256, 1024, flag);
    convT_kernel<<<(262144 + 255) / 256, 256, 0, stream>>>(d_in[12], pb + O_FC2W, 1024, 256, flag);

    const long T = T_TOK;
    unsigned short* xw       = r0;
    unsigned short* qkv      = r1;
    unsigned short* attn_out = r0;
    unsigned short* x2n      = r0;
    unsigned short* hidden   = r1;

    // LN1 + roll(-3,-3) + window partition
    ln_kernel<<<dim3(T / 4), 256, 0, stream>>>(d_in[0], pb + O_N1G, pb + O_N1B, xw, 0, flag);
    // qkv = xw @ qkv_w + qkv_b
    gemm_mfma<<<dim3(6, T / 128), 256, 0, stream>>>(xw, pb + O_QKVW, pb + O_QKVB, qkv,
                                                    nullptr, (int)T, 768, 256, 0,
                                                    nullptr, nullptr);
    // windowed MHA (MFMA): 16384 units / 4 waves per block
    attn_mfma<<<dim3(4096), 256, 0, stream>>>(qkv, pb + O_RELB, attn_out);
    // x2 = x + reverse(roll(proj(attn_out))) -> d_out
    gemm_mfma<<<dim3(2, T / 128), 256, 0, stream>>>(attn_out, pb + O_PROJW, pb + O_PROJB,
                                                    d_out, d_in[0], (int)T, 256, 256, 1,
                                                    flag, flag);
    // LN2
    ln_kernel<<<dim3(T / 4), 256, 0, stream>>>(d_out, pb + O_N2G, pb + O_N2B, x2n, 1, flag);
    // hidden = gelu(x2n @ fc1_w + fc1_b)
    gemm_mfma<<<dim3(8, T / 128), 256, 0, stream>>>(x2n, pb + O_FC1W, pb + O_FC1B, hidden,
                                                    nullptr, (int)T, 1024, 256, 2,
                                                    nullptr, nullptr);
    // out = x2 + hidden @ fc2_w + fc2_b
    gemm_mfma<<<dim3(2, T / 128), 256, 0, stream>>>(hidden, pb + O_FC2W, pb + O_FC2B, d_out,
                                                    d_out, (int)T, 256, 1024, 3,
                                                    nullptr, flag);
}

// Round 10
// 985.494 us; speedup vs baseline: 1.4746x; 1.4746x over previous
//
#include <hip/hip_runtime.h>
#include <math.h>

// ---- problem constants ----
// B=32, H=W=56, C=256, WS=7, SHIFT=3, HEADS=8, HD=32, HIDDEN=1024
// N=49 tokens/window, NW=64 windows/img, WT=2048 windows, T=100352 tokens
static constexpr long T_TOK = 100352;

typedef __attribute__((ext_vector_type(8))) short short8;
typedef __attribute__((ext_vector_type(8))) unsigned short ushort8v;
typedef __attribute__((ext_vector_type(4))) float floatx4;

__device__ __forceinline__ float b2f(unsigned short u) {
    return __uint_as_float(((unsigned)u) << 16);
}
__device__ __forceinline__ unsigned short f2b(float f) {
    unsigned u = __float_as_uint(f);
    u += 0x7FFFu + ((u >> 16) & 1u);     // round-to-nearest-even
    return (unsigned short)(u >> 16);
}

// async global->LDS, 16B per lane; LDS dest is wave-uniform base + lane*16
__device__ __forceinline__ void gload_lds16(const unsigned short* g, unsigned short* l) {
    __builtin_amdgcn_global_load_lds(
        (const __attribute__((address_space(1))) void*)g,
        (__attribute__((address_space(3))) void*)l, 16, 0, 0);
}

// ---- dtype detector: flag = 1 if inputs are fp32 (confirmed), 0 if bf16.
__global__ void detect_kernel(const unsigned short* __restrict__ x, int* flag) {
    __shared__ int cnt;
    if (threadIdx.x == 0) cnt = 0;
    __syncthreads();
    int local = 0;
    for (int i = 0; i < 16; ++i) {
        float a = fabsf(b2f(x[threadIdx.x * 16 + i]));
        if (a >= 0.015625f && a <= 8.0f) local++;
    }
    atomicAdd(&cnt, local);
    __syncthreads();
    if (threadIdx.x == 0) *flag = (cnt < 3072) ? 1 : 0;
}

// ---- normalize a param tensor to bf16 in ws ----
__global__ void conv_kernel(const void* __restrict__ src, unsigned short* __restrict__ dst,
                            int n, const int* __restrict__ flag) {
    int i = blockIdx.x * 256 + threadIdx.x;
    if (i >= n) return;
    if (*flag) dst[i] = f2b(((const float*)src)[i]);
    else       dst[i] = ((const unsigned short*)src)[i];
}

// ---- normalize + transpose weight [K][N] -> bf16 [N][K] ----
__global__ void convT_kernel(const void* __restrict__ src, unsigned short* __restrict__ dst,
                             int K, int N, const int* __restrict__ flag) {
    int i = blockIdx.x * 256 + threadIdx.x;
    if (i >= K * N) return;
    int k = i / N, n = i - k * N;
    unsigned short v = (*flag) ? f2b(((const float*)src)[i])
                               : ((const unsigned short*)src)[i];
    dst[(long)n * K + k] = v;
}

// ---------------- LayerNorm (one wave per token, 4 ch/lane) ----------------
__global__ __launch_bounds__(256) void ln_kernel(
    const void* __restrict__ xin,
    const unsigned short* __restrict__ g,
    const unsigned short* __restrict__ bsh,
    unsigned short* __restrict__ out, int mode, const int* __restrict__ flagp)
{
    int lane = threadIdx.x & 63;
    int wv = threadIdx.x >> 6;
    long t = (long)blockIdx.x * 4 + wv;
    int c0 = lane * 4;
    bool f32 = flagp && (*flagp != 0);
    float v0, v1, v2, v3;
    if (f32) {
        float4 xv = *(const float4*)((const float*)xin + t * 256 + c0);
        v0 = xv.x; v1 = xv.y; v2 = xv.z; v3 = xv.w;
    } else {
        ushort4 xv = *(const ushort4*)((const unsigned short*)xin + t * 256 + c0);
        v0 = b2f(xv.x); v1 = b2f(xv.y); v2 = b2f(xv.z); v3 = b2f(xv.w);
    }
    float s1 = v0 + v1 + v2 + v3;
    float s2 = v0*v0 + v1*v1 + v2*v2 + v3*v3;
    #pragma unroll
    for (int off = 32; off > 0; off >>= 1) {
        s1 += __shfl_down(s1, off, 64);
        s2 += __shfl_down(s2, off, 64);
    }
    s1 = __shfl(s1, 0, 64);
    s2 = __shfl(s2, 0, 64);
    float mean = s1 * (1.0f / 256.0f);
    float var  = s2 * (1.0f / 256.0f) - mean * mean;
    float rs = rsqrtf(fmaxf(var, 0.0f) + 1e-5f);
    ushort4 gv = *(const ushort4*)(g + c0);
    ushort4 bv = *(const ushort4*)(bsh + c0);
    ushort4 ov;
    ov.x = f2b((v0 - mean) * rs * b2f(gv.x) + b2f(bv.x));
    ov.y = f2b((v1 - mean) * rs * b2f(gv.y) + b2f(bv.y));
    ov.z = f2b((v2 - mean) * rs * b2f(gv.z) + b2f(bv.z));
    ov.w = f2b((v3 - mean) * rs * b2f(gv.w) + b2f(bv.w));
    long oidx;
    if (mode == 0) {
        int b_ = (int)(t / 3136);
        int hw = (int)(t % 3136);
        int hh = hw / 56, wc = hw % 56;
        int i = hh - 3; if (i < 0) i += 56;   // roll(-3)
        int j = wc - 3; if (j < 0) j += 56;
        oidx = ((long)(b_ * 64 + (i / 7) * 8 + (j / 7)) * 49
                + (i % 7) * 7 + (j % 7)) * 256 + c0;
    } else {
        oidx = t * 256 + c0;
    }
    *(ushort4*)(out + oidx) = ov;
}

// ------------- MFMA GEMM: 128x128 tile, 4 waves, bf16 in, fp32 acc -------------
// Counted-vmcnt 2-deep pipeline (T4): two K-tiles of global_load_lds in flight;
// per iteration drain only the OLDER tile with inline-asm s_waitcnt vmcnt(4)
// (never 0 in the loop), raw s_barrier (NOT __syncthreads, which emits
// vmcnt(0)), sched_barrier(0) fences pin ds_reads below the barrier.
// Loads for tile t+2 are issued at the bottom of iter t and not waited until
// the top of iter t+2 -> a full iteration of latency tolerance per tile.
// vmcnt accounting: 4 loads/STAGE/wave, outstanding <=8; vmcnt(4) retires
// exactly the older 4 (in-order retirement, m135). Last iter drains vmcnt(0).
__global__ __launch_bounds__(256) void gemm_mfma(
    const unsigned short* __restrict__ A,
    const unsigned short* __restrict__ Bt,
    const unsigned short* __restrict__ bias,
    void* __restrict__ out,
    const void* __restrict__ res,
    int M, int N, int K, int mode,
    const int* __restrict__ resflag, const int* __restrict__ oflag)
{
    __shared__ __align__(16) unsigned short lds[2][8192];  // per buf: As[128][32] | Bs[128][32]
    const int tid  = threadIdx.x;
    const int lane = tid & 63, wave = tid >> 6;
    const int q = lane >> 4, l16 = lane & 15;
    const int wm = wave >> 1, wn = wave & 1;

    // XCD swizzle (T1): consecutive swizzled ids share A-panels per XCD.
    const int gx  = (int)gridDim.x;
    const int nwg = gx * (int)gridDim.y;
    const int lin = (int)blockIdx.y * gx + (int)blockIdx.x;
    const int chunk = nwg >> 3;                 // nwg % 8 == 0 for all launches
    const int lin2 = (lin & 7) * chunk + (lin >> 3);
    const int bx = lin2 % gx, by = lin2 / gx;

    const long m0 = (long)by * 128;
    const int  n0 = bx * 128;

    // staging coords: thread covers 16B = 8 elems; row = t*64 + (tid>>2),
    // k-offset = (tid&3)*8. LDS linear elem offset within half-tile = tid*8.
    const int srow  = tid >> 2;         // 0..63
    const int skcol = (tid & 3) * 8;    // 0,8,16,24

    floatx4 acc[4][4];
    #pragma unroll
    for (int i = 0; i < 4; ++i)
        #pragma unroll
        for (int j = 0; j < 4; ++j)
            acc[i][j] = (floatx4){0.f, 0.f, 0.f, 0.f};

    const unsigned short* Ag = A  + (m0 + srow) * (long)K + skcol;
    const unsigned short* Bg = Bt + ((long)(n0 + srow)) * K + skcol;
    const long rowK64 = 64 * (long)K;
    const int  wbase  = wave * 512;     // wave-uniform LDS base (elems)

#define STAGE(b, t) do {                                       \
        const int k0_ = (t) << 5;                              \
        unsigned short* Lb = &lds[(b)][wbase];                 \
        gload_lds16(Ag + k0_,          Lb);                    \
        gload_lds16(Ag + k0_ + rowK64, Lb + 2048);             \
        gload_lds16(Bg + k0_,          Lb + 4096);             \
        gload_lds16(Bg + k0_ + rowK64, Lb + 6144);             \
    } while (0)
#define SBAR() do {                                            \
        __builtin_amdgcn_sched_barrier(0);                     \
        __builtin_amdgcn_s_barrier();                          \
        __builtin_amdgcn_sched_barrier(0);                     \
    } while (0)

    const int nt = K >> 5;              // 8 or 32; always >= 2
    STAGE(0, 0);
    STAGE(1, 1);
    int cur = 0;
    for (int t = 0; t < nt; ++t) {
        if (t + 1 < nt) asm volatile("s_waitcnt vmcnt(4)" ::: "memory");
        else            asm volatile("s_waitcnt vmcnt(0)" ::: "memory");
        SBAR();                          // tile t staged (all waves)
        short8 af[4], bfr[4];
        #pragma unroll
        for (int i = 0; i < 4; ++i)
            af[i] = *(const short8*)&lds[cur][(wm * 64 + i * 16 + l16) * 32 + q * 8];
        #pragma unroll
        for (int j = 0; j < 4; ++j)
            bfr[j] = *(const short8*)&lds[cur][4096 + (wn * 64 + j * 16 + l16) * 32 + q * 8];
        #pragma unroll
        for (int i = 0; i < 4; ++i)
            #pragma unroll
            for (int j = 0; j < 4; ++j)
                acc[i][j] = __builtin_amdgcn_mfma_f32_16x16x32_bf16(
                    af[i], bfr[j], acc[i][j], 0, 0, 0);
        SBAR();                          // all waves done reading buf[cur]
        if (t + 2 < nt) STAGE(cur, t + 2);   // stays in flight across barriers
        cur ^= 1;
    }
#undef STAGE
#undef SBAR

    const bool resf32 = resflag && (*resflag != 0);
    const bool outf32 = oflag && (*oflag != 0);
    unsigned short* outb = (unsigned short*)out;
    float* outf = (float*)out;
    #pragma unroll
    for (int i = 0; i < 4; ++i) {
        #pragma unroll
        for (int r = 0; r < 4; ++r) {
            long grow = m0 + wm * 64 + i * 16 + q * 4 + r;
            long natRow = 0;
            if (mode == 1) {
                int w = (int)(grow / 49), n = (int)(grow % 49);
                int b_ = w >> 6, widx = w & 63;
                int wi = widx >> 3, wj = widx & 7;
                int pi = n / 7, pj = n % 7;
                int ii = wi * 7 + pi, jj = wj * 7 + pj;
                int h = ii + 3; if (h >= 56) h -= 56;
                int wc = jj + 3; if (wc >= 56) wc -= 56;
                natRow = ((long)b_ * 3136 + h * 56 + wc);
            }
            #pragma unroll
            for (int j = 0; j < 4; ++j) {
                int gcol = n0 + wn * 64 + j * 16 + l16;
                float v = acc[i][j][r] + b2f(bias[gcol]);
                if (mode == 2) {
                    v = 0.5f * v * (1.0f + erff(v * 0.70710678118654752f));
                    outb[grow * N + gcol] = f2b(v);
                } else if (mode == 0) {
                    outb[grow * N + gcol] = f2b(v);
                } else if (mode == 3) {
                    long o = grow * N + gcol;
                    float rv = outf32 ? outf[o] : b2f(((const unsigned short*)res)[o]);
                    v += rv;
                    if (outf32) outf[o] = v; else outb[o] = f2b(v);
                } else { // mode 1
                    long o = natRow * 256 + gcol;
                    float rv = resf32 ? ((const float*)res)[o]
                                      : b2f(((const unsigned short*)res)[o]);
                    v += rv;
                    if (outf32) outf[o] = v; else outb[o] = f2b(v);
                }
            }
        }
    }
}

// ---------------- MFMA attention: one wave per (window, head) ----------------
// 49 -> padded 64. QK^T: 4x4 tiles of 16x16x32 (HD=32 = one K-step).
// Softmax in registers (row = 16 lanes x 4 regs, shfl_xor<16 stays in quad group).
// P: LDS round-trip C-layout -> [query][key] rows (stride 72 = 16B-aligned).
// V: staged transposed [d][key] (zero-padded past 49) as PV B-operand.
__global__ __launch_bounds__(256) void attn_mfma(
    const unsigned short* __restrict__ qkv,      // [WT*49, 768] bf16
    const unsigned short* __restrict__ rel_bias, // [169, 8] bf16
    unsigned short* __restrict__ out)            // [WT*49, 256] bf16
{
    __shared__ __align__(16) unsigned short bias_s[1360];
    __shared__ __align__(16) unsigned short Vt[4][32][72];
    __shared__ __align__(16) unsigned short Ps[4][64][72];
    const int tid = threadIdx.x;
    const int lane = tid & 63, wave = tid >> 6;
    const int q = lane >> 4, l16 = lane & 15;
    const int unit = blockIdx.x * 4 + wave;      // 0..16383
    const int w = unit >> 3, h = unit & 7;
    const int widx = w & 63, wi = widx >> 3, wj = widx & 7;

    for (int e = tid; e < 1352; e += 256) bias_s[e] = rel_bias[e];

    // stage V^T: Vt[d][key] = V[key][d]; zero for key >= 49 (LDS is uninit!)
    const long vbase = (long)w * 49 * 768 + 512 + h * 32;
    #pragma unroll 4
    for (int it = 0; it < 32; ++it) {
        int idx = it * 64 + lane;                // 0..2047
        int key = idx >> 5, d = idx & 31;
        unsigned short v = (key < 49) ? qkv[vbase + (long)key * 768 + d]
                                      : (unsigned short)0;
        Vt[wave][d][key] = v;
    }
    __syncthreads();

    // Q/K fragments straight from global (rows clamped to 48)
    const long qbase = (long)w * 49 * 768 + h * 32;
    short8 qf[4], kf[4];
    #pragma unroll
    for (int i = 0; i < 4; ++i) {
        int qr = l16 + 16 * i; if (qr > 48) qr = 48;
        qf[i] = *(const short8*)(qkv + qbase + (long)qr * 768 + q * 8);
    }
    #pragma unroll
    for (int j = 0; j < 4; ++j) {
        int kr = l16 + 16 * j; if (kr > 48) kr = 48;
        kf[j] = *(const short8*)(qkv + qbase + 256 + (long)kr * 768 + q * 8);
    }

    // scores: S[query][key], C-layout row=q*4+r(+16i), col=l16(+16j)
    floatx4 sc[4][4];
    #pragma unroll
    for (int i = 0; i < 4; ++i)
        #pragma unroll
        for (int j = 0; j < 4; ++j)
            sc[i][j] = __builtin_amdgcn_mfma_f32_16x16x32_bf16(
                qf[i], kf[j], (floatx4){0.f, 0.f, 0.f, 0.f}, 0, 0, 0);

    // key-side precompute (depends on j,l16 only)
    int imj[4], jmj[4], tmj[4], validj[4];
    #pragma unroll
    for (int j = 0; j < 4; ++j) {
        int key = 16 * j + l16;
        validj[j] = key < 49;
        int k2 = validj[j] ? key : 48;
        int im = k2 / 7, jm = k2 - im * 7;
        imj[j] = im; jmj[j] = jm;
        int rm = wi * 7 + im, cm = wj * 7 + jm;
        tmj[j] = (rm < 49 ? 0 : (rm < 53 ? 1 : 2)) * 3
               + (cm < 49 ? 0 : (cm < 53 ? 1 : 2));
    }

    const float scale = 0.17677669529663687f;    // HD^-0.5
    #pragma unroll
    for (int i = 0; i < 4; ++i) {
        #pragma unroll
        for (int r = 0; r < 4; ++r) {
            int query = 16 * i + 4 * q + r;
            int qn = query > 48 ? 48 : query;
            int in_ = qn / 7, jn = qn - in_ * 7;
            int rn = wi * 7 + in_, cn = wj * 7 + jn;
            int tn = (rn < 49 ? 0 : (rn < 53 ? 1 : 2)) * 3
                   + (cn < 49 ? 0 : (cn < 53 ? 1 : 2));
            float sv[4];
            float mx = -1e30f;
            #pragma unroll
            for (int j = 0; j < 4; ++j) {
                float s = sc[i][j][r] * scale;
                int ridx = (imj[j] - in_ + 6) * 13 + (jmj[j] - jn + 6);
                s += b2f(bias_s[ridx * 8 + h]);
                if (tmj[j] != tn) s -= 100.0f;
                if (!validj[j]) s = -1e30f;
                sv[j] = s;
                mx = fmaxf(mx, s);
            }
            #pragma unroll
            for (int m = 1; m < 16; m <<= 1)
                mx = fmaxf(mx, __shfl_xor(mx, m, 64));
            float sum = 0.0f;
            #pragma unroll
            for (int j = 0; j < 4; ++j) { sv[j] = __expf(sv[j] - mx); sum += sv[j]; }
            #pragma unroll
            for (int m = 1; m < 16; m <<= 1)
                sum += __shfl_xor(sum, m, 64);
            float inv = 1.0f / sum;
            #pragma unroll
            for (int j = 0; j < 4; ++j)
                Ps[wave][query][16 * j + l16] = f2b(sv[j] * inv);
        }
    }
    // wave-local LDS: compiler inserts lgkmcnt waits; no barrier needed.

    // PV: O[query][d] = P @ V. A=P from Ps rows, B=V from Vt rows.
    floatx4 oacc[4][2];
    #pragma unroll
    for (int i = 0; i < 4; ++i)
        #pragma unroll
        for (int jd = 0; jd < 2; ++jd)
            oacc[i][jd] = (floatx4){0.f, 0.f, 0.f, 0.f};
    #pragma unroll
    for (int s = 0; s < 2; ++s) {
        short8 vfr[2];
        #pragma unroll
        for (int jd = 0; jd < 2; ++jd)
            vfr[jd] = *(const short8*)&Vt[wave][l16 + 16 * jd][32 * s + q * 8];
        #pragma unroll
        for (int i = 0; i < 4; ++i) {
            short8 pfr = *(const short8*)&Ps[wave][l16 + 16 * i][32 * s + q * 8];
            #pragma unroll
            for (int jd = 0; jd < 2; ++jd)
                oacc[i][jd] = __builtin_amdgcn_mfma_f32_16x16x32_bf16(
                    pfr, vfr[jd], oacc[i][jd], 0, 0, 0);
        }
    }

    const long obase = (long)w * 49 * 256 + h * 32;
    #pragma unroll
    for (int i = 0; i < 4; ++i) {
        #pragma unroll
        for (int r = 0; r < 4; ++r) {
            int query = 16 * i + 4 * q + r;
            if (query < 49) {
                #pragma unroll
                for (int jd = 0; jd < 2; ++jd)
                    out[obase + (long)query * 256 + 16 * jd + l16] =
                        f2b(oacc[i][jd][r]);
            }
        }
    }
}

extern "C" void kernel_launch(void* const* d_in, const int* in_sizes, int n_in,
                              void* d_out, int out_size, void* d_ws, size_t ws_size,
                              hipStream_t stream) {
    (void)n_in; (void)out_size; (void)ws_size; (void)in_sizes;
    unsigned short* ws  = (unsigned short*)d_ws;
    const size_t TT = (size_t)T_TOK;

    unsigned short* r0  = ws;                        // [T,256]: xw / attn_out / x2n
    unsigned short* r1  = ws + TT * 256;             // [T,1024]: qkv then hidden
    unsigned short* pb  = ws + TT * 256 + TT * 1024; // params (weights transposed)
    const size_t O_QKVW = 0,      O_QKVB = 196608, O_RELB = 197376, O_PROJW = 198728;
    const size_t O_PROJB = 264264, O_N1G = 264520, O_N1B = 264776;
    const size_t O_N2G = 265032,  O_N2B = 265288, O_FC1W = 265544, O_FC1B = 527688;
    const size_t O_FC2W = 528712, O_FC2B = 790856, O_PEND = 791112;
    int* flag = (int*)(pb + O_PEND);

    detect_kernel<<<1, 256, 0, stream>>>((const unsigned short*)d_in[0], flag);

    struct { int idx; size_t off; int n; } cv[9] = {
        {1, O_N1G, 256}, {2, O_N1B, 256}, {4, O_QKVB, 768},
        {5, O_RELB, 1352}, {7, O_PROJB, 256},
        {8, O_N2G, 256}, {9, O_N2B, 256}, {11, O_FC1B, 1024}, {13, O_FC2B, 256},
    };
    for (int i = 0; i < 9; ++i)
        conv_kernel<<<(cv[i].n + 255) / 256, 256, 0, stream>>>(
            d_in[cv[i].idx], pb + cv[i].off, cv[i].n, flag);
    convT_kernel<<<(196608 + 255) / 256, 256, 0, stream>>>(d_in[3],  pb + O_QKVW, 256, 768,  flag);
    convT_kernel<<<(65536  + 255) / 256, 256, 0, stream>>>(d_in[6],  pb + O_PROJW, 256, 256, flag);
    convT_kernel<<<(262144 + 255) / 256, 256, 0, stream>>>(d_in[10], pb + O_FC1W, 256, 1024, flag);
    convT_kernel<<<(262144 + 255) / 256, 256, 0, stream>>>(d_in[12], pb + O_FC2W, 1024, 256, flag);

    const long T = T_TOK;
    unsigned short* xw       = r0;
    unsigned short* qkv      = r1;
    unsigned short* attn_out = r0;
    unsigned short* x2n      = r0;
    unsigned short* hidden   = r1;

    // LN1 + roll(-3,-3) + window partition
    ln_kernel<<<dim3(T / 4), 256, 0, stream>>>(d_in[0], pb + O_N1G, pb + O_N1B, xw, 0, flag);
    // qkv = xw @ qkv_w + qkv_b
    gemm_mfma<<<dim3(6, T / 128), 256, 0, stream>>>(xw, pb + O_QKVW, pb + O_QKVB, qkv,
                                                    nullptr, (int)T, 768, 256, 0,
                                                    nullptr, nullptr);
    // windowed MHA (MFMA): 16384 units / 4 waves per block
    attn_mfma<<<dim3(4096), 256, 0, stream>>>(qkv, pb + O_RELB, attn_out);
    // x2 = x + reverse(roll(proj(attn_out))) -> d_out
    gemm_mfma<<<dim3(2, T / 128), 256, 0, stream>>>(attn_out, pb + O_PROJW, pb + O_PROJB,
                                                    d_out, d_in[0], (int)T, 256, 256, 1,
                                                    flag, flag);
    // LN2
    ln_kernel<<<dim3(T / 4), 256, 0, stream>>>(d_out, pb + O_N2G, pb + O_N2B, x2n, 1, flag);
    // hidden = gelu(x2n @ fc1_w + fc1_b)
    gemm_mfma<<<dim3(8, T / 128), 256, 0, stream>>>(x2n, pb + O_FC1W, pb + O_FC1B, hidden,
                                                    nullptr, (int)T, 1024, 256, 2,
                                                    nullptr, nullptr);
    // out = x2 + hidden @ fc2_w + fc2_b
    gemm_mfma<<<dim3(2, T / 128), 256, 0, stream>>>(hidden, pb + O_FC2W, pb + O_FC2B, d_out,
                                                    d_out, (int)T, 256, 1024, 3,
                                                    nullptr, flag);
}